// Round 14
// baseline (653.643 us; speedup 1.0000x reference)
//
#include <hip/hip_runtime.h>
#include <hip/hip_bf16.h>
#include <cstdint>

// ---------------- constants ----------------
#define LQ 900
#define BB 16
#define CC 256
#define MM 8
#define CV 32
#define NROWS (LQ * BB)   // 14400

typedef __attribute__((ext_vector_type(8))) short short8;
typedef __attribute__((ext_vector_type(4))) float f32x4;

__device__ __forceinline__ short f2bf(float f) {
    union { float f; unsigned u; } x; x.f = f;
    const unsigned r = x.u + 0x7fff + ((x.u >> 16) & 1);
    return (short)(r >> 16);
}
__device__ __forceinline__ float bf2f(ushort u) {
    union { unsigned u; float f; } c; c.u = ((unsigned)u) << 16; return c.f;
}

// level geometry (square levels)
__device__ __constant__ int d_HW[4]    = {100, 50, 25, 13};
__device__ __constant__ int d_baseR[4] = {0, 160000, 200000, 210000};

// ---------------- merged weight prep: 8 transposes + bias concat, 1 launch ----
struct WPack {
    const float* W[8];
    ushort*      Wt[8];
    int K[8];
    int N[8];
    int cum[9];
    const float* offb;
    const float* awb;
    float*       obias;
};

__global__ __launch_bounds__(256) void conv_all(WPack p)
{
    const int bb = blockIdx.x;
    if (bb == p.cum[8]) {          // last block: bias concat
        for (int t = threadIdx.x; t < 384; t += 256)
            p.obias[t] = (t < 256) ? p.offb[t] : p.awb[t - 256];
        return;
    }
    int wi = 0;
    #pragma unroll
    for (int i = 0; i < 8; ++i)
        if (bb >= p.cum[i + 1]) wi = i + 1;
    const int ti  = bb - p.cum[wi];
    const int N   = p.N[wi], K = p.K[wi];
    const int ntx = N >> 5;
    const int n0  = (ti % ntx) * 32, k0 = (ti / ntx) * 32;
    const float* W  = p.W[wi];
    ushort*      Wt = p.Wt[wi];

    __shared__ float tl[32][33];
    const int t = threadIdx.x;
    const int tx = t & 31, ty = t >> 5;
    #pragma unroll
    for (int q = 0; q < 4; ++q)
        tl[ty + 8 * q][tx] = W[(size_t)(k0 + ty + 8 * q) * N + n0 + tx];
    __syncthreads();
    #pragma unroll
    for (int q = 0; q < 4; ++q)
        Wt[(size_t)(n0 + ty + 8 * q) * K + k0 + tx] = (ushort)f2bf(tl[tx][ty + 8 * q]);
}

// ---------------- bf16 MFMA GEMM core (device fn; proven engine) ----------------
#define EPS 136
#define LDSN 17408

template<bool A_BF16, bool ADD_A2, bool RELU, bool RESID, bool RESID_BF16, bool OUT_BF16>
__device__ __forceinline__ void gemm_core(
    ushort* lds,
    const void* __restrict__ Ap, const float* __restrict__ A2, int lda,
    const ushort* __restrict__ Bt, const float* __restrict__ bias,
    const void* __restrict__ resid, void* __restrict__ Cp, int ldc,
    int Mr, int Kd, int row0, int col0)
{
    ushort* As = lds;
    ushort* Bs = lds + 8192;

    const int t = threadIdx.x;
    const int lane = t & 63;
    const int w = t >> 6;
    const int wr = w >> 1, wc = w & 1;
    const int lr = lane & 15, lk = lane >> 4;

    f32x4 acc[4][4] = {};

    const int srow = t >> 4;
    const int skq  = (t & 15) * 4;
    const int sg   = (t & 15) >> 1;
    const int srem = (t & 1) * 8;

    const float*  Af = (const float*)Ap;
    const ushort* Ah = (const ushort*)Ap;

    short4 sa_[8], sb_[8];
    float4 fa_[8], f2_[8];

    const int nk = Kd >> 6;

    auto issue = [&](int kk0) {
        #pragma unroll
        for (int p = 0; p < 8; ++p) {
            const int gr = min(row0 + p * 16 + srow, Mr - 1);
            if constexpr (A_BF16) {
                sa_[p] = *reinterpret_cast<const short4*>(Ah + (size_t)gr * lda + kk0 + skq);
            } else {
                fa_[p] = *reinterpret_cast<const float4*>(Af + (size_t)gr * lda + kk0 + skq);
                if constexpr (ADD_A2)
                    f2_[p] = *reinterpret_cast<const float4*>(A2 + (size_t)gr * lda + kk0 + skq);
            }
            sb_[p] = *reinterpret_cast<const short4*>(Bt + (size_t)(col0 + p * 16 + srow) * Kd + kk0 + skq);
        }
    };

    issue(0);

    for (int kt = 0; kt < nk; ++kt) {
        #pragma unroll
        for (int p = 0; p < 8; ++p) {
            const int r = p * 16 + srow;
            short4 a4;
            if constexpr (A_BF16) {
                a4 = sa_[p];
            } else {
                float4 av = fa_[p];
                if constexpr (ADD_A2) {
                    av.x += f2_[p].x; av.y += f2_[p].y; av.z += f2_[p].z; av.w += f2_[p].w;
                }
                a4.x = f2bf(av.x); a4.y = f2bf(av.y); a4.z = f2bf(av.z); a4.w = f2bf(av.w);
            }
            const int byteA = r * 128 + ((sg ^ (r & 7)) << 4) + srem;
            *reinterpret_cast<short4*>((char*)As + byteA) = a4;
            *reinterpret_cast<short4*>((char*)Bs + byteA) = sb_[p];
        }
        __syncthreads();

        if (kt + 1 < nk) issue((kt + 1) * 64);

        #pragma unroll
        for (int kk = 0; kk < 2; ++kk) {
            short8 af[4], bfr[4];
            #pragma unroll
            for (int i = 0; i < 4; ++i) {
                const int r = wr * 64 + i * 16 + lr;
                const int byte = r * 128 + (((kk * 4 + lk) ^ (r & 7)) << 4);
                af[i] = *reinterpret_cast<const short8*>((char*)As + byte);
            }
            #pragma unroll
            for (int j = 0; j < 4; ++j) {
                const int r = wc * 64 + j * 16 + lr;
                const int byte = r * 128 + (((kk * 4 + lk) ^ (r & 7)) << 4);
                bfr[j] = *reinterpret_cast<const short8*>((char*)Bs + byte);
            }
            #pragma unroll
            for (int i = 0; i < 4; ++i)
                #pragma unroll
                for (int j = 0; j < 4; ++j)
                    acc[i][j] = __builtin_amdgcn_mfma_f32_16x16x32_bf16(af[i], bfr[j], acc[i][j], 0, 0, 0);
        }
        __syncthreads();
    }

    if constexpr (OUT_BF16) {
        ushort* Cb = (ushort*)Cp;
        #pragma unroll
        for (int j = 0; j < 4; ++j) {
            const int lcol = wc * 64 + j * 16 + lr;
            const float bcol = bias[col0 + lcol];
            #pragma unroll
            for (int i = 0; i < 4; ++i) {
                const int lrbase = wr * 64 + i * 16 + lk * 4;
                #pragma unroll
                for (int reg = 0; reg < 4; ++reg) {
                    float v = acc[i][j][reg] + bcol;
                    if (RELU) v = fmaxf(v, 0.f);
                    lds[(lrbase + reg) * EPS + lcol] = (ushort)f2bf(v);
                }
            }
        }
        __syncthreads();
        const int erow = t >> 1, ehalf = t & 1;
        if (row0 + erow < Mr) {
            ushort* dst = Cb + (size_t)(row0 + erow) * ldc + col0 + ehalf * 64;
            const ushort* src = lds + erow * EPS + ehalf * 64;
            #pragma unroll
            for (int q = 0; q < 8; ++q)
                *reinterpret_cast<short8*>(dst + q * 8) =
                    *reinterpret_cast<const short8*>(src + q * 8);
        }
    } else {
        float* Cf = (float*)Cp;
        #pragma unroll
        for (int j = 0; j < 4; ++j) {
            const int col = col0 + wc * 64 + j * 16 + lr;
            const float bcol = bias[col];
            #pragma unroll
            for (int i = 0; i < 4; ++i) {
                const int rbase = row0 + wr * 64 + i * 16 + lk * 4;
                #pragma unroll
                for (int reg = 0; reg < 4; ++reg) {
                    const int r = rbase + reg;
                    if (r < Mr) {
                        float v = acc[i][j][reg] + bcol;
                        if (RESID) {
                            if (RESID_BF16)
                                v += bf2f(((const ushort*)resid)[(size_t)r * ldc + col]);
                            else
                                v += ((const float*)resid)[(size_t)r * ldc + col];
                        }
                        if (RELU) v = fmaxf(v, 0.f);
                        Cf[(size_t)r * ldc + col] = v;
                    }
                }
            }
        }
    }
}

template<bool A_BF16, bool ADD_A2, bool RELU, bool RESID, bool RESID_BF16, bool OUT_BF16>
__global__ __launch_bounds__(256) void gemm_bf16(
    const void* __restrict__ Ap, const float* __restrict__ A2, int lda,
    const ushort* __restrict__ Bt, const float* __restrict__ bias,
    const void* __restrict__ resid, void* __restrict__ Cp, int ldc,
    int Mr, int Kd)
{
    __shared__ ushort lds[LDSN];
    gemm_core<A_BF16, ADD_A2, RELU, RESID, RESID_BF16, OUT_BF16>(
        lds, Ap, A2, lda, Bt, bias, resid, Cp, ldc, Mr, Kd,
        blockIdx.y * 128, blockIdx.x * 128);
}

// ---------------- val_gemm4: barrier-free per-wave value projection ----------------
// C[64 x 256] per block; wave w owns cols w*64..w*64+64. A/B fragments loaded
// DIRECTLY from global (no main-loop LDS, no barriers): per fragment, lanes
// {lr, 16+lr, 32+lr, 48+lr} read consecutive 16B chunks of one row -> full 64B
// granules. 4 waves share A rows via L1 (16KB/k-step). Epilogue stages the
// 64x256 bf16 tile in LDS (row stride 270 ushorts == 7 dwords -> conflict-free
// readback: wave = 64-col chunk, lane = row), then 128B/lane coalesced stores.
__global__ __launch_bounds__(256) void val_gemm4(
    const float* __restrict__ Af, const float* __restrict__ A2,
    const ushort* __restrict__ Bt, const float* __restrict__ bias,
    ushort* __restrict__ C, int Mr)
{
    __shared__ ushort clds[64 * 270];
    const int t = threadIdx.x;
    const int w = t >> 6, lane = t & 63;
    const int lr = lane & 15, lk = lane >> 4;
    const int row0 = blockIdx.x * 64;
    const int wcol = w * 64;

    int gr[4];
    #pragma unroll
    for (int i = 0; i < 4; ++i) gr[i] = min(row0 + i * 16 + lr, Mr - 1);

    f32x4 acc[4][4] = {};   // [i][j]: rows i*16+lk*4+reg, cols wcol+j*16+lr

    for (int kt = 0; kt < 8; ++kt) {
        const int k0 = kt * 32 + lk * 8;
        short8 afr[4];
        #pragma unroll
        for (int i = 0; i < 4; ++i) {
            const float* fp = Af + (size_t)gr[i] * 256 + k0;
            const float* pp = A2 + (size_t)gr[i] * 256 + k0;
            const float4 f0 = *reinterpret_cast<const float4*>(fp);
            const float4 f1 = *reinterpret_cast<const float4*>(fp + 4);
            const float4 p0 = *reinterpret_cast<const float4*>(pp);
            const float4 p1 = *reinterpret_cast<const float4*>(pp + 4);
            short8 a;
            a[0] = f2bf(f0.x + p0.x); a[1] = f2bf(f0.y + p0.y);
            a[2] = f2bf(f0.z + p0.z); a[3] = f2bf(f0.w + p0.w);
            a[4] = f2bf(f1.x + p1.x); a[5] = f2bf(f1.y + p1.y);
            a[6] = f2bf(f1.z + p1.z); a[7] = f2bf(f1.w + p1.w);
            afr[i] = a;
        }
        short8 bfr[4];
        #pragma unroll
        for (int j = 0; j < 4; ++j)
            bfr[j] = *reinterpret_cast<const short8*>(
                Bt + (size_t)(wcol + j * 16 + lr) * 256 + k0);
        #pragma unroll
        for (int i = 0; i < 4; ++i)
            #pragma unroll
            for (int j = 0; j < 4; ++j)
                acc[i][j] = __builtin_amdgcn_mfma_f32_16x16x32_bf16(afr[i], bfr[j], acc[i][j], 0, 0, 0);
    }

    // epilogue: +bias, stage bf16 tile in LDS
    #pragma unroll
    for (int j = 0; j < 4; ++j) {
        const int col = wcol + j * 16 + lr;
        const float bcol = bias[col];
        #pragma unroll
        for (int i = 0; i < 4; ++i)
            #pragma unroll
            for (int reg = 0; reg < 4; ++reg)
                clds[(i * 16 + lk * 4 + reg) * 270 + col] =
                    (ushort)f2bf(acc[i][j][reg] + bcol);
    }
    __syncthreads();
    // wave w -> col chunk w*64..+64, lane -> row: 128B per lane, contiguous
    if (row0 + lane < Mr) {
        ushort* dst = C + (size_t)(row0 + lane) * 256 + w * 64;
        const ushort* src = clds + lane * 270 + w * 64;
        #pragma unroll
        for (int q = 0; q < 8; ++q)
            *reinterpret_cast<short8*>(dst + q * 8) =
                *reinterpret_cast<const short8*>(src + q * 8);
    }
}

// ---------------- MHA: bf16 MFMA flash attention ----------------
__global__ __launch_bounds__(256) void attn_mfma(
    const ushort* __restrict__ QKbf, const ushort* __restrict__ Vbf,
    ushort* __restrict__ attnO)
{
    __shared__ ushort K_lds[64][40];
    __shared__ ushort Vt[32][72];
    __shared__ ushort P_lds[4][16][72];

    const int t = threadIdx.x;
    const int w = t >> 6, lane = t & 63;
    const int q0 = blockIdx.x * 64;
    const int m = blockIdx.y & 7, b = blockIdx.y >> 3;

    const int lr = lane & 15;
    const int lk = lane >> 4;

    const int qrow = min(q0 + w * 16 + lr, LQ - 1);
    const short8 qf = *reinterpret_cast<const short8*>(
        QKbf + ((size_t)qrow * BB + b) * 512 + m * 32 + lk * 8);

    f32x4 oacc[2] = {f32x4{0.f,0.f,0.f,0.f}, f32x4{0.f,0.f,0.f,0.f}};
    float mrun[4] = {-1e30f, -1e30f, -1e30f, -1e30f};
    float lrun[4] = {0.f, 0.f, 0.f, 0.f};

    const float scale = 0.17677669529663687f; // 1/sqrt(32)
    const int sr = t >> 2;
    const int sd = (t & 3) * 8;

    for (int k0 = 0; k0 < LQ; k0 += 64) {
        {
            const int kr = min(k0 + sr, LQ - 1);
            *reinterpret_cast<short8*>(&K_lds[sr][sd]) =
                *reinterpret_cast<const short8*>(QKbf + ((size_t)kr * BB + b) * 512 + 256 + m * 32 + sd);
            const short8 v8 = *reinterpret_cast<const short8*>(
                Vbf + ((size_t)kr * BB + b) * 256 + m * 32 + sd);
            #pragma unroll
            for (int j = 0; j < 8; ++j) Vt[sd + j][sr] = (ushort)v8[j];
        }
        __syncthreads();

        f32x4 sa[4];
        #pragma unroll
        for (int n = 0; n < 4; ++n) {
            const short8 kf = *reinterpret_cast<const short8*>(&K_lds[n * 16 + lr][lk * 8]);
            sa[n] = __builtin_amdgcn_mfma_f32_16x16x32_bf16(qf, kf, f32x4{0.f,0.f,0.f,0.f}, 0, 0, 0);
        }
        #pragma unroll
        for (int n = 0; n < 4; ++n)
            #pragma unroll
            for (int r = 0; r < 4; ++r)
                sa[n][r] *= scale;
        if (k0 + 64 > LQ) {
            #pragma unroll
            for (int n = 0; n < 4; ++n)
                if (k0 + n * 16 + lr >= LQ) {
                    #pragma unroll
                    for (int r = 0; r < 4; ++r) sa[n][r] = -1e30f;
                }
        }

        #pragma unroll
        for (int r = 0; r < 4; ++r) {
            float mx = fmaxf(fmaxf(sa[0][r], sa[1][r]), fmaxf(sa[2][r], sa[3][r]));
            #pragma unroll
            for (int o = 8; o; o >>= 1) mx = fmaxf(mx, __shfl_xor(mx, o));
            const float mnew = fmaxf(mrun[r], mx);
            const float corr = __expf(mrun[r] - mnew);
            mrun[r] = mnew;
            float psum = 0.f;
            #pragma unroll
            for (int n = 0; n < 4; ++n) {
                const float p = __expf(sa[n][r] - mnew);
                psum += p;
                P_lds[w][lk * 4 + r][n * 16 + lr] = (ushort)f2bf(p);
            }
            #pragma unroll
            for (int o = 8; o; o >>= 1) psum += __shfl_xor(psum, o);
            lrun[r] = lrun[r] * corr + psum;
            oacc[0][r] *= corr;
            oacc[1][r] *= corr;
        }

        #pragma unroll
        for (int kk = 0; kk < 2; ++kk) {
            const short8 pf = *reinterpret_cast<const short8*>(&P_lds[w][lr][kk * 32 + lk * 8]);
            #pragma unroll
            for (int dt = 0; dt < 2; ++dt) {
                const short8 vf = *reinterpret_cast<const short8*>(&Vt[dt * 16 + lr][kk * 32 + lk * 8]);
                oacc[dt] = __builtin_amdgcn_mfma_f32_16x16x32_bf16(pf, vf, oacc[dt], 0, 0, 0);
            }
        }
        __syncthreads();
    }

    #pragma unroll
    for (int r = 0; r < 4; ++r) {
        const int row = q0 + w * 16 + lk * 4 + r;
        if (row < LQ) {
            const float inv = 1.f / lrun[r];
            ushort* op = attnO + ((size_t)row * BB + b) * 256 + m * 32;
            op[lr]      = (ushort)f2bf(oacc[0][r] * inv);
            op[16 + lr] = (ushort)f2bf(oacc[1][r] * inv);
        }
    }
}

// ---------------- layernorm: one wave per row of 256 ----------------
template<bool OUT_BF16>
__global__ __launch_bounds__(256) void ln_kernel(
    const float* __restrict__ X, const float* __restrict__ g,
    const float* __restrict__ bta, void* __restrict__ Y, int nrows)
{
    const int r = blockIdx.x * 4 + (threadIdx.x >> 6);
    if (r >= nrows) return;
    const int lane = threadIdx.x & 63;
    const float4 v = *reinterpret_cast<const float4*>(X + (size_t)r * 256 + lane * 4);
    float s  = v.x + v.y + v.z + v.w;
    float sq = v.x * v.x + v.y * v.y + v.z * v.z + v.w * v.w;
    #pragma unroll
    for (int o = 32; o; o >>= 1) { s += __shfl_xor(s, o); sq += __shfl_xor(sq, o); }
    const float mean = s * (1.f / 256.f);
    const float var  = sq * (1.f / 256.f) - mean * mean;
    const float rs   = rsqrtf(var + 1e-5f);
    const float4 gv = *reinterpret_cast<const float4*>(g + lane * 4);
    const float4 bv = *reinterpret_cast<const float4*>(bta + lane * 4);
    float4 o4;
    o4.x = (v.x - mean) * rs * gv.x + bv.x;
    o4.y = (v.y - mean) * rs * gv.y + bv.y;
    o4.z = (v.z - mean) * rs * gv.z + bv.z;
    o4.w = (v.w - mean) * rs * gv.w + bv.w;
    if (OUT_BF16) {
        short4 u;
        u.x = f2bf(o4.x); u.y = f2bf(o4.y); u.z = f2bf(o4.z); u.w = f2bf(o4.w);
        *reinterpret_cast<short4*>((ushort*)Y + (size_t)r * 256 + lane * 4) = u;
    } else {
        *reinterpret_cast<float4*>((float*)Y + (size_t)r * 256 + lane * 4) = o4;
    }
}

// ---------------- fused sampling: prep (softmax+bilinear) + gather ----------------
__global__ __launch_bounds__(256) void samp_gather(
    const ushort* __restrict__ Vval, const float* __restrict__ obf,
    const float* __restrict__ ref, ushort* __restrict__ samp)
{
    __shared__ int   sI[4][16][4];
    __shared__ float sW[4][16][4];

    const int w    = threadIdx.x >> 6;
    const int lane = threadIdx.x & 63;
    const int wid  = blockIdx.x * 4 + w;           // < 115,200
    const int q  = wid % LQ;
    const int bm = wid / LQ;
    const int m  = bm & 7, b = bm >> 3;
    const int row = q * BB + b;

    if (lane < 16) {
        const float logit = obf[(size_t)row * 384 + 256 + m * 16 + lane];
        float mx = logit;
        #pragma unroll
        for (int o = 1; o < 16; o <<= 1) mx = fmaxf(mx, __shfl_xor(mx, o));
        const float e = __expf(logit - mx);
        float se = e;
        #pragma unroll
        for (int o = 1; o < 16; o <<= 1) se += __shfl_xor(se, o);
        const float aw = e / se;

        const int   l  = lane >> 2;
        const int   Hl = d_HW[l];
        const float Hf = (float)Hl;
        const int   gbase = d_baseR[l] + b * Hl * Hl;
        const float rx = ref[row * 2 + 0], ry = ref[row * 2 + 1];
        const float ox = obf[(size_t)row * 384 + m * 32 + lane * 2 + 0];
        const float oy = obf[(size_t)row * 384 + m * 32 + lane * 2 + 1];
        const float px = rx * Hf - 0.5f + ox;
        const float py = ry * Hf - 0.5f + oy;
        const float x0 = floorf(px), y0 = floorf(py);

        #pragma unroll
        for (int c = 0; c < 4; ++c) {
            const float xi = x0 + (float)(c & 1);
            const float yi = y0 + (float)(c >> 1);
            const float wv = (1.f - fabsf(px - xi)) * (1.f - fabsf(py - yi));
            const bool valid = (xi >= 0.f) && (xi < Hf) && (yi >= 0.f) && (yi < Hf);
            const int ix = min(max((int)xi, 0), Hl - 1);
            const int iy = min(max((int)yi, 0), Hl - 1);
            sI[w][lane][c] = gbase + iy * Hl + ix;
            sW[w][lane][c] = valid ? aw * wv : 0.f;
        }
    }
    // same-wave LDS write->read: program order + compiler waitcnt; no barrier needed.

    const int sid = lane >> 3, dg = lane & 7;
    const uint2* V4 = (const uint2*)Vval;
    const int coff  = m * 8 + dg;

    float a0 = 0.f, a1 = 0.f, a2 = 0.f, a3 = 0.f;
    #pragma unroll
    for (int g = 0; g < 2; ++g) {
        const int s = g * 8 + sid;
        const int4   I = *reinterpret_cast<const int4*>(&sI[w][s][0]);
        const float4 W = *reinterpret_cast<const float4*>(&sW[w][s][0]);
        uint2 v;
        v = V4[(size_t)I.x * 64 + coff];
        a0 += W.x * bf2f((ushort)v.x); a1 += W.x * bf2f((ushort)(v.x >> 16));
        a2 += W.x * bf2f((ushort)v.y); a3 += W.x * bf2f((ushort)(v.y >> 16));
        v = V4[(size_t)I.y * 64 + coff];
        a0 += W.y * bf2f((ushort)v.x); a1 += W.y * bf2f((ushort)(v.x >> 16));
        a2 += W.y * bf2f((ushort)v.y); a3 += W.y * bf2f((ushort)(v.y >> 16));
        v = V4[(size_t)I.z * 64 + coff];
        a0 += W.z * bf2f((ushort)v.x); a1 += W.z * bf2f((ushort)(v.x >> 16));
        a2 += W.z * bf2f((ushort)v.y); a3 += W.z * bf2f((ushort)(v.y >> 16));
        v = V4[(size_t)I.w * 64 + coff];
        a0 += W.w * bf2f((ushort)v.x); a1 += W.w * bf2f((ushort)(v.x >> 16));
        a2 += W.w * bf2f((ushort)v.y); a3 += W.w * bf2f((ushort)(v.y >> 16));
    }
    #pragma unroll
    for (int o = 8; o <= 32; o <<= 1) {
        a0 += __shfl_xor(a0, o); a1 += __shfl_xor(a1, o);
        a2 += __shfl_xor(a2, o); a3 += __shfl_xor(a3, o);
    }
    if (sid == 0) {
        short4 u;
        u.x = f2bf(a0); u.y = f2bf(a1); u.z = f2bf(a2); u.w = f2bf(a3);
        *reinterpret_cast<short4*>(samp + (size_t)row * 256 + m * 32 + dg * 4) = u;
    }
}

// ---------------- launcher ----------------
extern "C" void kernel_launch(void* const* d_in, const int* in_sizes, int n_in,
                              void* d_out, int out_size, void* d_ws, size_t ws_size,
                              hipStream_t stream)
{
    const float* qo   = (const float*)d_in[0];
    const float* qpz  = (const float*)d_in[1];
    const float* refp = (const float*)d_in[2];
    const float* feat[4] = {(const float*)d_in[3], (const float*)d_in[5],
                            (const float*)d_in[7], (const float*)d_in[9]};
    const float* pos[4]  = {(const float*)d_in[4], (const float*)d_in[6],
                            (const float*)d_in[8], (const float*)d_in[10]};
    const float* sa_in_w  = (const float*)d_in[11];
    const float* sa_in_b  = (const float*)d_in[12];
    const float* sa_out_w = (const float*)d_in[13];
    const float* sa_out_b = (const float*)d_in[14];
    const float* n1_g = (const float*)d_in[15];
    const float* n1_b = (const float*)d_in[16];
    const float* n2_g = (const float*)d_in[17];
    const float* n2_b = (const float*)d_in[18];
    const float* n3_g = (const float*)d_in[19];
    const float* n3_b = (const float*)d_in[20];
    const float* val_w  = (const float*)d_in[21];
    const float* val_b  = (const float*)d_in[22];
    const float* off_w  = (const float*)d_in[23];
    const float* off_b  = (const float*)d_in[24];
    const float* aw_w   = (const float*)d_in[25];
    const float* aw_b   = (const float*)d_in[26];
    const float* dout_w = (const float*)d_in[27];
    const float* dout_b = (const float*)d_in[28];
    const float* ffn_w1 = (const float*)d_in[29];
    const float* ffn_b1 = (const float*)d_in[30];
    const float* ffn_w2 = (const float*)d_in[31];
    const float* ffn_b2 = (const float*)d_in[32];

    char* ws = (char*)d_ws;
    // bf16 buffers (R11 layout)
    ushort* QKbf   = (ushort*)(ws + 0);             // 14,745,600
    ushort* Vbf    = (ushort*)(ws + 14745600);      // 7,372,800
    ushort* attnO  = (ushort*)(ws + 22118400);      // 7,372,800
    ushort* Vval   = (ushort*)(ws + 29491200);      // 108,904,448
    ushort* WsaInT = (ushort*)(ws + 138395648);     // 393,216
    ushort* WsaOutT= (ushort*)(ws + 138788864);     // 131,072
    ushort* WvalT  = (ushort*)(ws + 138919936);     // 131,072
    ushort* WdoutT = (ushort*)(ws + 139051008);     // 131,072
    ushort* Wffn1T = (ushort*)(ws + 139182080);     // 524,288
    ushort* Wffn2T = (ushort*)(ws + 139706368);     // 524,288
    ushort* WoffAwT= (ushort*)(ws + 140230656);     // 196,608
    float*  obias  = (float*)(ws + 140427264);      // 2,048
    // mixed buffers
    float*  x1   = (float*)(ws + 140429312);        // 14,745,600 (f32)
    float*  dres = x1;
    ushort* xln1 = (ushort*)(ws + 155174912);       // 7,372,800 (bf16)
    float*  obf  = (float*)(ws + 162547712);        // 22,118,400 (f32)
    ushort* samp = (ushort*)(ws + 184666112);       // 7,372,800 (bf16)
    ushort* xln2 = (ushort*)(ws + 192038912);       // 7,372,800 (bf16)
    ushort* h    = (ushort*)(ws + 199411712);       // 29,491,200 (bf16)
    float*  x3   = (float*)(ws + 228902912);        // 14,745,600 (f32) -> ends 243,648,512

    const dim3 blk(256);
    const int GM = (NROWS + 127) / 128;             // 113

    // 0. all weight transposes + bias concat in ONE launch
    WPack wp;
    wp.W[0] = sa_in_w;  wp.Wt[0] = WsaInT;  wp.K[0] = 256;  wp.N[0] = 768;
    wp.W[1] = sa_out_w; wp.Wt[1] = WsaOutT; wp.K[1] = 256;  wp.N[1] = 256;
    wp.W[2] = val_w;    wp.Wt[2] = WvalT;   wp.K[2] = 256;  wp.N[2] = 256;
    wp.W[3] = dout_w;   wp.Wt[3] = WdoutT;  wp.K[3] = 256;  wp.N[3] = 256;
    wp.W[4] = ffn_w1;   wp.Wt[4] = Wffn1T;  wp.K[4] = 256;  wp.N[4] = 1024;
    wp.W[5] = ffn_w2;   wp.Wt[5] = Wffn2T;  wp.K[5] = 1024; wp.N[5] = 256;
    wp.W[6] = off_w;    wp.Wt[6] = WoffAwT; wp.K[6] = 256;  wp.N[6] = 256;
    wp.W[7] = aw_w;     wp.Wt[7] = WoffAwT + 256 * 256; wp.K[7] = 256; wp.N[7] = 128;
    const int cums[9] = {0, 192, 256, 320, 384, 640, 896, 960, 992};
    for (int i = 0; i < 9; ++i) wp.cum[i] = cums[i];
    wp.offb = off_b; wp.awb = aw_b; wp.obias = obias;
    conv_all<<<dim3(993), blk, 0, stream>>>(wp);

    // 1. Q,K projections (A = qo+qpz, fp32 fused add) -> QKbf
    gemm_bf16<false, true, false, false, false, true><<<dim3(4, GM), blk, 0, stream>>>(
        qo, qpz, 256, WsaInT, sa_in_b, nullptr, QKbf, 512, NROWS, 256);
    // 2. V projection (A = qo fp32) -> Vbf
    gemm_bf16<false, false, false, false, false, true><<<dim3(2, GM), blk, 0, stream>>>(
        qo, nullptr, 256, WsaInT + 512 * 256, sa_in_b + 512, nullptr, Vbf, 256, NROWS, 256);
    // 3. self-attention
    attn_mfma<<<dim3(15, 128), blk, 0, stream>>>(QKbf, Vbf, attnO);
    // 4. out projection + residual(qo f32) -> x1 f32
    gemm_bf16<true, false, false, true, false, false><<<dim3(2, GM), blk, 0, stream>>>(
        attnO, nullptr, 256, WsaOutT, sa_out_b, qo, x1, 256, NROWS, 256);
    // 5. LN1 -> xln1 bf16
    ln_kernel<true><<<dim3(3600), blk, 0, stream>>>(x1, n1_g, n1_b, xln1, NROWS);
    // 6. fused offsets + aw logits -> obf f32 (N=384), A = xln1 bf16
    gemm_bf16<true, false, false, false, false, false><<<dim3(3, GM), blk, 0, stream>>>(
        xln1, nullptr, 256, WoffAwT, obias, nullptr, obf, 384, NROWS, 256);
    // 7. value projections per level (barrier-free per-wave GEMM) -> Vval bf16
    val_gemm4<<<dim3(2500), blk, 0, stream>>>(
        feat[0], pos[0], WvalT, val_b, Vval, 160000);
    val_gemm4<<<dim3(625), blk, 0, stream>>>(
        feat[1], pos[1], WvalT, val_b, Vval + (size_t)160000 * 256, 40000);
    val_gemm4<<<dim3(157), blk, 0, stream>>>(
        feat[2], pos[2], WvalT, val_b, Vval + (size_t)200000 * 256, 10000);
    val_gemm4<<<dim3(43), blk, 0, stream>>>(
        feat[3], pos[3], WvalT, val_b, Vval + (size_t)210000 * 256, 2704);
    // 8. fused prep+gather -> samp bf16
    samp_gather<<<dim3(28800), blk, 0, stream>>>(Vval, obf, refp, samp);
    // 9. deform output projection (A=samp bf16) + residual(xln1 bf16) -> dres f32
    gemm_bf16<true, false, false, true, true, false><<<dim3(2, GM), blk, 0, stream>>>(
        samp, nullptr, 256, WdoutT, dout_b, xln1, dres, 256, NROWS, 256);
    // 10. LN2 -> xln2 bf16
    ln_kernel<true><<<dim3(3600), blk, 0, stream>>>(dres, n2_g, n2_b, xln2, NROWS);
    // 11. FFN1 (relu), A = xln2 bf16 -> h bf16
    gemm_bf16<true, false, true, false, false, true><<<dim3(8, GM), blk, 0, stream>>>(
        xln2, nullptr, 256, Wffn1T, ffn_b1, nullptr, h, 1024, NROWS, 256);
    // 12. FFN2 + residual(xln2 bf16) -> x3 f32
    gemm_bf16<true, false, false, true, true, false><<<dim3(2, GM), blk, 0, stream>>>(
        h, nullptr, 1024, Wffn2T, ffn_b2, xln2, x3, 256, NROWS, 1024);
    // 13. LN3 -> output f32
    ln_kernel<false><<<dim3(3600), blk, 0, stream>>>(x3, n3_g, n3_b, (float*)d_out, NROWS);
}

// Round 15
// 528.572 us; speedup vs baseline: 1.2366x; 1.2366x over previous
//
#include <hip/hip_runtime.h>
#include <hip/hip_bf16.h>
#include <cstdint>

// ---------------- constants ----------------
#define LQ 900
#define BB 16
#define CC 256
#define MM 8
#define CV 32
#define NROWS (LQ * BB)   // 14400

typedef __attribute__((ext_vector_type(8))) short short8;
typedef __attribute__((ext_vector_type(4))) float f32x4;

__device__ __forceinline__ short f2bf(float f) {
    union { float f; unsigned u; } x; x.f = f;
    const unsigned r = x.u + 0x7fff + ((x.u >> 16) & 1);
    return (short)(r >> 16);
}
__device__ __forceinline__ float bf2f(ushort u) {
    union { unsigned u; float f; } c; c.u = ((unsigned)u) << 16; return c.f;
}

// level geometry (square levels)
__device__ __constant__ int d_HW[4]    = {100, 50, 25, 13};
__device__ __constant__ int d_baseR[4] = {0, 160000, 200000, 210000};

// ---------------- merged weight prep: 8 transposes + bias concat, 1 launch ----
struct WPack {
    const float* W[8];
    ushort*      Wt[8];
    int K[8];
    int N[8];
    int cum[9];
    const float* offb;
    const float* awb;
    float*       obias;
};

__global__ __launch_bounds__(256) void conv_all(WPack p)
{
    const int bb = blockIdx.x;
    if (bb == p.cum[8]) {          // last block: bias concat
        for (int t = threadIdx.x; t < 384; t += 256)
            p.obias[t] = (t < 256) ? p.offb[t] : p.awb[t - 256];
        return;
    }
    int wi = 0;
    #pragma unroll
    for (int i = 0; i < 8; ++i)
        if (bb >= p.cum[i + 1]) wi = i + 1;
    const int ti  = bb - p.cum[wi];
    const int N   = p.N[wi], K = p.K[wi];
    const int ntx = N >> 5;
    const int n0  = (ti % ntx) * 32, k0 = (ti / ntx) * 32;
    const float* W  = p.W[wi];
    ushort*      Wt = p.Wt[wi];

    __shared__ float tl[32][33];
    const int t = threadIdx.x;
    const int tx = t & 31, ty = t >> 5;
    #pragma unroll
    for (int q = 0; q < 4; ++q)
        tl[ty + 8 * q][tx] = W[(size_t)(k0 + ty + 8 * q) * N + n0 + tx];
    __syncthreads();
    #pragma unroll
    for (int q = 0; q < 4; ++q)
        Wt[(size_t)(n0 + ty + 8 * q) * K + k0 + tx] = (ushort)f2bf(tl[tx][ty + 8 * q]);
}

// ---------------- bf16 MFMA GEMM core (device fn; proven engine) ----------------
#define EPS 136
#define LDSN 17408

template<bool A_BF16, bool ADD_A2, bool RELU, bool RESID, bool RESID_BF16, bool OUT_BF16>
__device__ __forceinline__ void gemm_core(
    ushort* lds,
    const void* __restrict__ Ap, const float* __restrict__ A2, int lda,
    const ushort* __restrict__ Bt, const float* __restrict__ bias,
    const void* __restrict__ resid, void* __restrict__ Cp, int ldc,
    int Mr, int Kd, int row0, int col0)
{
    ushort* As = lds;
    ushort* Bs = lds + 8192;

    const int t = threadIdx.x;
    const int lane = t & 63;
    const int w = t >> 6;
    const int wr = w >> 1, wc = w & 1;
    const int lr = lane & 15, lk = lane >> 4;

    f32x4 acc[4][4] = {};

    const int srow = t >> 4;
    const int skq  = (t & 15) * 4;
    const int sg   = (t & 15) >> 1;
    const int srem = (t & 1) * 8;

    const float*  Af = (const float*)Ap;
    const ushort* Ah = (const ushort*)Ap;

    short4 sa_[8], sb_[8];
    float4 fa_[8], f2_[8];

    const int nk = Kd >> 6;

    auto issue = [&](int kk0) {
        #pragma unroll
        for (int p = 0; p < 8; ++p) {
            const int gr = min(row0 + p * 16 + srow, Mr - 1);
            if constexpr (A_BF16) {
                sa_[p] = *reinterpret_cast<const short4*>(Ah + (size_t)gr * lda + kk0 + skq);
            } else {
                fa_[p] = *reinterpret_cast<const float4*>(Af + (size_t)gr * lda + kk0 + skq);
                if constexpr (ADD_A2)
                    f2_[p] = *reinterpret_cast<const float4*>(A2 + (size_t)gr * lda + kk0 + skq);
            }
            sb_[p] = *reinterpret_cast<const short4*>(Bt + (size_t)(col0 + p * 16 + srow) * Kd + kk0 + skq);
        }
    };

    issue(0);

    for (int kt = 0; kt < nk; ++kt) {
        #pragma unroll
        for (int p = 0; p < 8; ++p) {
            const int r = p * 16 + srow;
            short4 a4;
            if constexpr (A_BF16) {
                a4 = sa_[p];
            } else {
                float4 av = fa_[p];
                if constexpr (ADD_A2) {
                    av.x += f2_[p].x; av.y += f2_[p].y; av.z += f2_[p].z; av.w += f2_[p].w;
                }
                a4.x = f2bf(av.x); a4.y = f2bf(av.y); a4.z = f2bf(av.z); a4.w = f2bf(av.w);
            }
            const int byteA = r * 128 + ((sg ^ (r & 7)) << 4) + srem;
            *reinterpret_cast<short4*>((char*)As + byteA) = a4;
            *reinterpret_cast<short4*>((char*)Bs + byteA) = sb_[p];
        }
        __syncthreads();

        if (kt + 1 < nk) issue((kt + 1) * 64);

        #pragma unroll
        for (int kk = 0; kk < 2; ++kk) {
            short8 af[4], bfr[4];
            #pragma unroll
            for (int i = 0; i < 4; ++i) {
                const int r = wr * 64 + i * 16 + lr;
                const int byte = r * 128 + (((kk * 4 + lk) ^ (r & 7)) << 4);
                af[i] = *reinterpret_cast<const short8*>((char*)As + byte);
            }
            #pragma unroll
            for (int j = 0; j < 4; ++j) {
                const int r = wc * 64 + j * 16 + lr;
                const int byte = r * 128 + (((kk * 4 + lk) ^ (r & 7)) << 4);
                bfr[j] = *reinterpret_cast<const short8*>((char*)Bs + byte);
            }
            #pragma unroll
            for (int i = 0; i < 4; ++i)
                #pragma unroll
                for (int j = 0; j < 4; ++j)
                    acc[i][j] = __builtin_amdgcn_mfma_f32_16x16x32_bf16(af[i], bfr[j], acc[i][j], 0, 0, 0);
        }
        __syncthreads();
    }

    if constexpr (OUT_BF16) {
        ushort* Cb = (ushort*)Cp;
        #pragma unroll
        for (int j = 0; j < 4; ++j) {
            const int lcol = wc * 64 + j * 16 + lr;
            const float bcol = bias[col0 + lcol];
            #pragma unroll
            for (int i = 0; i < 4; ++i) {
                const int lrbase = wr * 64 + i * 16 + lk * 4;
                #pragma unroll
                for (int reg = 0; reg < 4; ++reg) {
                    float v = acc[i][j][reg] + bcol;
                    if (RELU) v = fmaxf(v, 0.f);
                    lds[(lrbase + reg) * EPS + lcol] = (ushort)f2bf(v);
                }
            }
        }
        __syncthreads();
        const int erow = t >> 1, ehalf = t & 1;
        if (row0 + erow < Mr) {
            ushort* dst = Cb + (size_t)(row0 + erow) * ldc + col0 + ehalf * 64;
            const ushort* src = lds + erow * EPS + ehalf * 64;
            #pragma unroll
            for (int q = 0; q < 8; ++q)
                *reinterpret_cast<short8*>(dst + q * 8) =
                    *reinterpret_cast<const short8*>(src + q * 8);
        }
    } else {
        float* Cf = (float*)Cp;
        #pragma unroll
        for (int j = 0; j < 4; ++j) {
            const int col = col0 + wc * 64 + j * 16 + lr;
            const float bcol = bias[col];
            #pragma unroll
            for (int i = 0; i < 4; ++i) {
                const int rbase = row0 + wr * 64 + i * 16 + lk * 4;
                #pragma unroll
                for (int reg = 0; reg < 4; ++reg) {
                    const int r = rbase + reg;
                    if (r < Mr) {
                        float v = acc[i][j][reg] + bcol;
                        if (RESID) {
                            if (RESID_BF16)
                                v += bf2f(((const ushort*)resid)[(size_t)r * ldc + col]);
                            else
                                v += ((const float*)resid)[(size_t)r * ldc + col];
                        }
                        if (RELU) v = fmaxf(v, 0.f);
                        Cf[(size_t)r * ldc + col] = v;
                    }
                }
            }
        }
    }
}

template<bool A_BF16, bool ADD_A2, bool RELU, bool RESID, bool RESID_BF16, bool OUT_BF16>
__global__ __launch_bounds__(256) void gemm_bf16(
    const void* __restrict__ Ap, const float* __restrict__ A2, int lda,
    const ushort* __restrict__ Bt, const float* __restrict__ bias,
    const void* __restrict__ resid, void* __restrict__ Cp, int ldc,
    int Mr, int Kd)
{
    __shared__ ushort lds[LDSN];
    gemm_core<A_BF16, ADD_A2, RELU, RESID, RESID_BF16, OUT_BF16>(
        lds, Ap, A2, lda, Bt, bias, resid, Cp, ldc, Mr, Kd,
        blockIdx.y * 128, blockIdx.x * 128);
}

// ---------------- MHA: bf16 MFMA flash attention ----------------
__global__ __launch_bounds__(256) void attn_mfma(
    const ushort* __restrict__ QKbf, const ushort* __restrict__ Vbf,
    ushort* __restrict__ attnO)
{
    __shared__ ushort K_lds[64][40];
    __shared__ ushort Vt[32][72];
    __shared__ ushort P_lds[4][16][72];

    const int t = threadIdx.x;
    const int w = t >> 6, lane = t & 63;
    const int q0 = blockIdx.x * 64;
    const int m = blockIdx.y & 7, b = blockIdx.y >> 3;

    const int lr = lane & 15;
    const int lk = lane >> 4;

    const int qrow = min(q0 + w * 16 + lr, LQ - 1);
    const short8 qf = *reinterpret_cast<const short8*>(
        QKbf + ((size_t)qrow * BB + b) * 512 + m * 32 + lk * 8);

    f32x4 oacc[2] = {f32x4{0.f,0.f,0.f,0.f}, f32x4{0.f,0.f,0.f,0.f}};
    float mrun[4] = {-1e30f, -1e30f, -1e30f, -1e30f};
    float lrun[4] = {0.f, 0.f, 0.f, 0.f};

    const float scale = 0.17677669529663687f; // 1/sqrt(32)
    const int sr = t >> 2;
    const int sd = (t & 3) * 8;

    for (int k0 = 0; k0 < LQ; k0 += 64) {
        {
            const int kr = min(k0 + sr, LQ - 1);
            *reinterpret_cast<short8*>(&K_lds[sr][sd]) =
                *reinterpret_cast<const short8*>(QKbf + ((size_t)kr * BB + b) * 512 + 256 + m * 32 + sd);
            const short8 v8 = *reinterpret_cast<const short8*>(
                Vbf + ((size_t)kr * BB + b) * 256 + m * 32 + sd);
            #pragma unroll
            for (int j = 0; j < 8; ++j) Vt[sd + j][sr] = (ushort)v8[j];
        }
        __syncthreads();

        f32x4 sa[4];
        #pragma unroll
        for (int n = 0; n < 4; ++n) {
            const short8 kf = *reinterpret_cast<const short8*>(&K_lds[n * 16 + lr][lk * 8]);
            sa[n] = __builtin_amdgcn_mfma_f32_16x16x32_bf16(qf, kf, f32x4{0.f,0.f,0.f,0.f}, 0, 0, 0);
        }
        #pragma unroll
        for (int n = 0; n < 4; ++n)
            #pragma unroll
            for (int r = 0; r < 4; ++r)
                sa[n][r] *= scale;
        if (k0 + 64 > LQ) {
            #pragma unroll
            for (int n = 0; n < 4; ++n)
                if (k0 + n * 16 + lr >= LQ) {
                    #pragma unroll
                    for (int r = 0; r < 4; ++r) sa[n][r] = -1e30f;
                }
        }

        #pragma unroll
        for (int r = 0; r < 4; ++r) {
            float mx = fmaxf(fmaxf(sa[0][r], sa[1][r]), fmaxf(sa[2][r], sa[3][r]));
            #pragma unroll
            for (int o = 8; o; o >>= 1) mx = fmaxf(mx, __shfl_xor(mx, o));
            const float mnew = fmaxf(mrun[r], mx);
            const float corr = __expf(mrun[r] - mnew);
            mrun[r] = mnew;
            float psum = 0.f;
            #pragma unroll
            for (int n = 0; n < 4; ++n) {
                const float p = __expf(sa[n][r] - mnew);
                psum += p;
                P_lds[w][lk * 4 + r][n * 16 + lr] = (ushort)f2bf(p);
            }
            #pragma unroll
            for (int o = 8; o; o >>= 1) psum += __shfl_xor(psum, o);
            lrun[r] = lrun[r] * corr + psum;
            oacc[0][r] *= corr;
            oacc[1][r] *= corr;
        }

        #pragma unroll
        for (int kk = 0; kk < 2; ++kk) {
            const short8 pf = *reinterpret_cast<const short8*>(&P_lds[w][lr][kk * 32 + lk * 8]);
            #pragma unroll
            for (int dt = 0; dt < 2; ++dt) {
                const short8 vf = *reinterpret_cast<const short8*>(&Vt[dt * 16 + lr][kk * 32 + lk * 8]);
                oacc[dt] = __builtin_amdgcn_mfma_f32_16x16x32_bf16(pf, vf, oacc[dt], 0, 0, 0);
            }
        }
        __syncthreads();
    }

    #pragma unroll
    for (int r = 0; r < 4; ++r) {
        const int row = q0 + w * 16 + lk * 4 + r;
        if (row < LQ) {
            const float inv = 1.f / lrun[r];
            ushort* op = attnO + ((size_t)row * BB + b) * 256 + m * 32;
            op[lr]      = (ushort)f2bf(oacc[0][r] * inv);
            op[16 + lr] = (ushort)f2bf(oacc[1][r] * inv);
        }
    }
}

// ---------------- layernorm: one wave per row of 256 ----------------
template<bool OUT_BF16>
__global__ __launch_bounds__(256) void ln_kernel(
    const float* __restrict__ X, const float* __restrict__ g,
    const float* __restrict__ bta, void* __restrict__ Y, int nrows)
{
    const int r = blockIdx.x * 4 + (threadIdx.x >> 6);
    if (r >= nrows) return;
    const int lane = threadIdx.x & 63;
    const float4 v = *reinterpret_cast<const float4*>(X + (size_t)r * 256 + lane * 4);
    float s  = v.x + v.y + v.z + v.w;
    float sq = v.x * v.x + v.y * v.y + v.z * v.z + v.w * v.w;
    #pragma unroll
    for (int o = 32; o; o >>= 1) { s += __shfl_xor(s, o); sq += __shfl_xor(sq, o); }
    const float mean = s * (1.f / 256.f);
    const float var  = sq * (1.f / 256.f) - mean * mean;
    const float rs   = rsqrtf(var + 1e-5f);
    const float4 gv = *reinterpret_cast<const float4*>(g + lane * 4);
    const float4 bv = *reinterpret_cast<const float4*>(bta + lane * 4);
    float4 o4;
    o4.x = (v.x - mean) * rs * gv.x + bv.x;
    o4.y = (v.y - mean) * rs * gv.y + bv.y;
    o4.z = (v.z - mean) * rs * gv.z + bv.z;
    o4.w = (v.w - mean) * rs * gv.w + bv.w;
    if (OUT_BF16) {
        short4 u;
        u.x = f2bf(o4.x); u.y = f2bf(o4.y); u.z = f2bf(o4.z); u.w = f2bf(o4.w);
        *reinterpret_cast<short4*>((ushort*)Y + (size_t)r * 256 + lane * 4) = u;
    } else {
        *reinterpret_cast<float4*>((float*)Y + (size_t)r * 256 + lane * 4) = o4;
    }
}

// ---------------- fused sampling: prep (softmax+bilinear) + gather ----------------
// obf (NROWS,384) bf16: cols 0..255 offsets, 256..383 aw logits.
__global__ __launch_bounds__(256) void samp_gather(
    const ushort* __restrict__ Vval, const ushort* __restrict__ obf,
    const float* __restrict__ ref, ushort* __restrict__ samp)
{
    __shared__ int   sI[4][16][4];
    __shared__ float sW[4][16][4];

    const int w    = threadIdx.x >> 6;
    const int lane = threadIdx.x & 63;
    const int wid  = blockIdx.x * 4 + w;           // < 115,200
    const int q  = wid % LQ;
    const int bm = wid / LQ;
    const int m  = bm & 7, b = bm >> 3;
    const int row = q * BB + b;

    if (lane < 16) {
        const float logit = bf2f(obf[(size_t)row * 384 + 256 + m * 16 + lane]);
        float mx = logit;
        #pragma unroll
        for (int o = 1; o < 16; o <<= 1) mx = fmaxf(mx, __shfl_xor(mx, o));
        const float e = __expf(logit - mx);
        float se = e;
        #pragma unroll
        for (int o = 1; o < 16; o <<= 1) se += __shfl_xor(se, o);
        const float aw = e / se;

        const int   l  = lane >> 2;
        const int   Hl = d_HW[l];
        const float Hf = (float)Hl;
        const int   gbase = d_baseR[l] + b * Hl * Hl;
        const float rx = ref[row * 2 + 0], ry = ref[row * 2 + 1];
        const float ox = bf2f(obf[(size_t)row * 384 + m * 32 + lane * 2 + 0]);
        const float oy = bf2f(obf[(size_t)row * 384 + m * 32 + lane * 2 + 1]);
        const float px = rx * Hf - 0.5f + ox;
        const float py = ry * Hf - 0.5f + oy;
        const float x0 = floorf(px), y0 = floorf(py);

        #pragma unroll
        for (int c = 0; c < 4; ++c) {
            const float xi = x0 + (float)(c & 1);
            const float yi = y0 + (float)(c >> 1);
            const float wv = (1.f - fabsf(px - xi)) * (1.f - fabsf(py - yi));
            const bool valid = (xi >= 0.f) && (xi < Hf) && (yi >= 0.f) && (yi < Hf);
            const int ix = min(max((int)xi, 0), Hl - 1);
            const int iy = min(max((int)yi, 0), Hl - 1);
            sI[w][lane][c] = gbase + iy * Hl + ix;
            sW[w][lane][c] = valid ? aw * wv : 0.f;
        }
    }
    // same-wave LDS write->read: program order + compiler waitcnt; no barrier needed.

    const int sid = lane >> 3, dg = lane & 7;
    const uint2* V4 = (const uint2*)Vval;
    const int coff  = m * 8 + dg;

    float a0 = 0.f, a1 = 0.f, a2 = 0.f, a3 = 0.f;
    #pragma unroll
    for (int g = 0; g < 2; ++g) {
        const int s = g * 8 + sid;
        const int4   I = *reinterpret_cast<const int4*>(&sI[w][s][0]);
        const float4 W = *reinterpret_cast<const float4*>(&sW[w][s][0]);
        uint2 v;
        v = V4[(size_t)I.x * 64 + coff];
        a0 += W.x * bf2f((ushort)v.x); a1 += W.x * bf2f((ushort)(v.x >> 16));
        a2 += W.x * bf2f((ushort)v.y); a3 += W.x * bf2f((ushort)(v.y >> 16));
        v = V4[(size_t)I.y * 64 + coff];
        a0 += W.y * bf2f((ushort)v.x); a1 += W.y * bf2f((ushort)(v.x >> 16));
        a2 += W.y * bf2f((ushort)v.y); a3 += W.y * bf2f((ushort)(v.y >> 16));
        v = V4[(size_t)I.z * 64 + coff];
        a0 += W.z * bf2f((ushort)v.x); a1 += W.z * bf2f((ushort)(v.x >> 16));
        a2 += W.z * bf2f((ushort)v.y); a3 += W.z * bf2f((ushort)(v.y >> 16));
        v = V4[(size_t)I.w * 64 + coff];
        a0 += W.w * bf2f((ushort)v.x); a1 += W.w * bf2f((ushort)(v.x >> 16));
        a2 += W.w * bf2f((ushort)v.y); a3 += W.w * bf2f((ushort)(v.y >> 16));
    }
    #pragma unroll
    for (int o = 8; o <= 32; o <<= 1) {
        a0 += __shfl_xor(a0, o); a1 += __shfl_xor(a1, o);
        a2 += __shfl_xor(a2, o); a3 += __shfl_xor(a3, o);
    }
    if (sid == 0) {
        short4 u;
        u.x = f2bf(a0); u.y = f2bf(a1); u.z = f2bf(a2); u.w = f2bf(a3);
        *reinterpret_cast<short4*>(samp + (size_t)row * 256 + m * 32 + dg * 4) = u;
    }
}

// ---------------- launcher ----------------
extern "C" void kernel_launch(void* const* d_in, const int* in_sizes, int n_in,
                              void* d_out, int out_size, void* d_ws, size_t ws_size,
                              hipStream_t stream)
{
    const float* qo   = (const float*)d_in[0];
    const float* qpz  = (const float*)d_in[1];
    const float* refp = (const float*)d_in[2];
    const float* feat[4] = {(const float*)d_in[3], (const float*)d_in[5],
                            (const float*)d_in[7], (const float*)d_in[9]};
    const float* pos[4]  = {(const float*)d_in[4], (const float*)d_in[6],
                            (const float*)d_in[8], (const float*)d_in[10]};
    const float* sa_in_w  = (const float*)d_in[11];
    const float* sa_in_b  = (const float*)d_in[12];
    const float* sa_out_w = (const float*)d_in[13];
    const float* sa_out_b = (const float*)d_in[14];
    const float* n1_g = (const float*)d_in[15];
    const float* n1_b = (const float*)d_in[16];
    const float* n2_g = (const float*)d_in[17];
    const float* n2_b = (const float*)d_in[18];
    const float* n3_g = (const float*)d_in[19];
    const float* n3_b = (const float*)d_in[20];
    const float* val_w  = (const float*)d_in[21];
    const float* val_b  = (const float*)d_in[22];
    const float* off_w  = (const float*)d_in[23];
    const float* off_b  = (const float*)d_in[24];
    const float* aw_w   = (const float*)d_in[25];
    const float* aw_b   = (const float*)d_in[26];
    const float* dout_w = (const float*)d_in[27];
    const float* dout_b = (const float*)d_in[28];
    const float* ffn_w1 = (const float*)d_in[29];
    const float* ffn_b1 = (const float*)d_in[30];
    const float* ffn_w2 = (const float*)d_in[31];
    const float* ffn_b2 = (const float*)d_in[32];

    char* ws = (char*)d_ws;
    // bf16 buffers (R11 layout)
    ushort* QKbf   = (ushort*)(ws + 0);             // 14,745,600
    ushort* Vbf    = (ushort*)(ws + 14745600);      // 7,372,800
    ushort* attnO  = (ushort*)(ws + 22118400);      // 7,372,800
    ushort* Vval   = (ushort*)(ws + 29491200);      // 108,904,448
    ushort* WsaInT = (ushort*)(ws + 138395648);     // 393,216
    ushort* WsaOutT= (ushort*)(ws + 138788864);     // 131,072
    ushort* WvalT  = (ushort*)(ws + 138919936);     // 131,072
    ushort* WdoutT = (ushort*)(ws + 139051008);     // 131,072
    ushort* Wffn1T = (ushort*)(ws + 139182080);     // 524,288
    ushort* Wffn2T = (ushort*)(ws + 139706368);     // 524,288
    ushort* WoffAwT= (ushort*)(ws + 140230656);     // 196,608
    float*  obias  = (float*)(ws + 140427264);      // 2,048
    // mixed buffers
    float*  x1   = (float*)(ws + 140429312);        // 14,745,600 (f32)
    float*  dres = x1;
    ushort* xln1 = (ushort*)(ws + 155174912);       // 7,372,800 (bf16)
    ushort* obf  = (ushort*)(ws + 162547712);       // 11,059,200 (bf16, (NROWS,384))
    ushort* samp = (ushort*)(ws + 173606912);       // 7,372,800 (bf16)
    ushort* xln2 = (ushort*)(ws + 180979712);       // 7,372,800 (bf16)
    ushort* h    = (ushort*)(ws + 188352512);       // 29,491,200 (bf16)
    float*  x3   = (float*)(ws + 217843712);        // 14,745,600 (f32) -> ends 232,589,312

    const dim3 blk(256);
    const int GM = (NROWS + 127) / 128;             // 113

    // 0. all weight transposes + bias concat in ONE launch
    WPack wp;
    wp.W[0] = sa_in_w;  wp.Wt[0] = WsaInT;  wp.K[0] = 256;  wp.N[0] = 768;
    wp.W[1] = sa_out_w; wp.Wt[1] = WsaOutT; wp.K[1] = 256;  wp.N[1] = 256;
    wp.W[2] = val_w;    wp.Wt[2] = WvalT;   wp.K[2] = 256;  wp.N[2] = 256;
    wp.W[3] = dout_w;   wp.Wt[3] = WdoutT;  wp.K[3] = 256;  wp.N[3] = 256;
    wp.W[4] = ffn_w1;   wp.Wt[4] = Wffn1T;  wp.K[4] = 256;  wp.N[4] = 1024;
    wp.W[5] = ffn_w2;   wp.Wt[5] = Wffn2T;  wp.K[5] = 1024; wp.N[5] = 256;
    wp.W[6] = off_w;    wp.Wt[6] = WoffAwT; wp.K[6] = 256;  wp.N[6] = 256;
    wp.W[7] = aw_w;     wp.Wt[7] = WoffAwT + 256 * 256; wp.K[7] = 256; wp.N[7] = 128;
    const int cums[9] = {0, 192, 256, 320, 384, 640, 896, 960, 992};
    for (int i = 0; i < 9; ++i) wp.cum[i] = cums[i];
    wp.offb = off_b; wp.awb = aw_b; wp.obias = obias;
    conv_all<<<dim3(993), blk, 0, stream>>>(wp);

    // 1. Q,K projections (A = qo+qpz, fp32 fused add) -> QKbf
    gemm_bf16<false, true, false, false, false, true><<<dim3(4, GM), blk, 0, stream>>>(
        qo, qpz, 256, WsaInT, sa_in_b, nullptr, QKbf, 512, NROWS, 256);
    // 2. V projection (A = qo fp32) -> Vbf
    gemm_bf16<false, false, false, false, false, true><<<dim3(2, GM), blk, 0, stream>>>(
        qo, nullptr, 256, WsaInT + 512 * 256, sa_in_b + 512, nullptr, Vbf, 256, NROWS, 256);
    // 3. self-attention
    attn_mfma<<<dim3(15, 128), blk, 0, stream>>>(QKbf, Vbf, attnO);
    // 4. out projection + residual(qo f32) -> x1 f32
    gemm_bf16<true, false, false, true, false, false><<<dim3(2, GM), blk, 0, stream>>>(
        attnO, nullptr, 256, WsaOutT, sa_out_b, qo, x1, 256, NROWS, 256);
    // 5. LN1 -> xln1 bf16
    ln_kernel<true><<<dim3(3600), blk, 0, stream>>>(x1, n1_g, n1_b, xln1, NROWS);
    // 6. fused offsets + aw logits -> obf bf16 (N=384), A = xln1 bf16
    gemm_bf16<true, false, false, false, false, true><<<dim3(3, GM), blk, 0, stream>>>(
        xln1, nullptr, 256, WoffAwT, obias, nullptr, obf, 384, NROWS, 256);
    // 7. value projections per level (proven 2-phase engine, fp32 fused add)
    gemm_bf16<false, true, false, false, false, true><<<dim3(2, 1250), blk, 0, stream>>>(
        feat[0], pos[0], 256, WvalT, val_b, nullptr, Vval, 256, 160000, 256);
    gemm_bf16<false, true, false, false, false, true><<<dim3(2, 313), blk, 0, stream>>>(
        feat[1], pos[1], 256, WvalT, val_b, nullptr, Vval + (size_t)160000 * 256, 256, 40000, 256);
    gemm_bf16<false, true, false, false, false, true><<<dim3(2, 79), blk, 0, stream>>>(
        feat[2], pos[2], 256, WvalT, val_b, nullptr, Vval + (size_t)200000 * 256, 256, 10000, 256);
    gemm_bf16<false, true, false, false, false, true><<<dim3(2, 22), blk, 0, stream>>>(
        feat[3], pos[3], 256, WvalT, val_b, nullptr, Vval + (size_t)210000 * 256, 256, 2704, 256);
    // 8. fused prep+gather -> samp bf16
    samp_gather<<<dim3(28800), blk, 0, stream>>>(Vval, obf, refp, samp);
    // 9. deform output projection (A=samp bf16) + residual(xln1 bf16) -> dres f32
    gemm_bf16<true, false, false, true, true, false><<<dim3(2, GM), blk, 0, stream>>>(
        samp, nullptr, 256, WdoutT, dout_b, xln1, dres, 256, NROWS, 256);
    // 10. LN2 -> xln2 bf16
    ln_kernel<true><<<dim3(3600), blk, 0, stream>>>(dres, n2_g, n2_b, xln2, NROWS);
    // 11. FFN1 (relu), A = xln2 bf16 -> h bf16
    gemm_bf16<true, false, true, false, false, true><<<dim3(8, GM), blk, 0, stream>>>(
        xln2, nullptr, 256, Wffn1T, ffn_b1, nullptr, h, 1024, NROWS, 256);
    // 12. FFN2 + residual(xln2 bf16) -> x3 f32
    gemm_bf16<true, false, false, true, true, false><<<dim3(2, GM), blk, 0, stream>>>(
        h, nullptr, 1024, Wffn2T, ffn_b2, xln2, x3, 256, NROWS, 1024);
    // 13. LN3 -> output f32
    ln_kernel<false><<<dim3(3600), blk, 0, stream>>>(x3, n3_g, n3_b, (float*)d_out, NROWS);
}

// Round 16
// 490.780 us; speedup vs baseline: 1.3318x; 1.0770x over previous
//
#include <hip/hip_runtime.h>
#include <hip/hip_bf16.h>
#include <cstdint>

// ---------------- constants ----------------
#define LQ 900
#define BB 16
#define CC 256
#define MM 8
#define CV 32
#define NROWS (LQ * BB)   // 14400

typedef __attribute__((ext_vector_type(8))) short short8;
typedef __attribute__((ext_vector_type(4))) float f32x4;

__device__ __forceinline__ short f2bf(float f) {
    union { float f; unsigned u; } x; x.f = f;
    const unsigned r = x.u + 0x7fff + ((x.u >> 16) & 1);
    return (short)(r >> 16);
}
__device__ __forceinline__ float bf2f(ushort u) {
    union { unsigned u; float f; } c; c.u = ((unsigned)u) << 16; return c.f;
}

// level geometry (square levels)
__device__ __constant__ int d_HW[4]    = {100, 50, 25, 13};
__device__ __constant__ int d_baseR[4] = {0, 160000, 200000, 210000};

// ---------------- merged weight prep: 8 transposes + bias concat, 1 launch ----
struct WPack {
    const float* W[8];
    ushort*      Wt[8];
    int K[8];
    int N[8];
    int cum[9];
    const float* offb;
    const float* awb;
    float*       obias;
};

__global__ __launch_bounds__(256) void conv_all(WPack p)
{
    const int bb = blockIdx.x;
    if (bb == p.cum[8]) {          // last block: bias concat
        for (int t = threadIdx.x; t < 384; t += 256)
            p.obias[t] = (t < 256) ? p.offb[t] : p.awb[t - 256];
        return;
    }
    int wi = 0;
    #pragma unroll
    for (int i = 0; i < 8; ++i)
        if (bb >= p.cum[i + 1]) wi = i + 1;
    const int ti  = bb - p.cum[wi];
    const int N   = p.N[wi], K = p.K[wi];
    const int ntx = N >> 5;
    const int n0  = (ti % ntx) * 32, k0 = (ti / ntx) * 32;
    const float* W  = p.W[wi];
    ushort*      Wt = p.Wt[wi];

    __shared__ float tl[32][33];
    const int t = threadIdx.x;
    const int tx = t & 31, ty = t >> 5;
    #pragma unroll
    for (int q = 0; q < 4; ++q)
        tl[ty + 8 * q][tx] = W[(size_t)(k0 + ty + 8 * q) * N + n0 + tx];
    __syncthreads();
    #pragma unroll
    for (int q = 0; q < 4; ++q)
        Wt[(size_t)(n0 + ty + 8 * q) * K + k0 + tx] = (ushort)f2bf(tl[tx][ty + 8 * q]);
}

// ---------------- bf16 MFMA GEMM core (device fn; proven engine) ----------------
#define EPS 136
#define LDSN 17408

template<bool A_BF16, bool ADD_A2, bool RELU, bool RESID, bool RESID_BF16, bool OUT_BF16>
__device__ __forceinline__ void gemm_core(
    ushort* lds,
    const void* __restrict__ Ap, const float* __restrict__ A2, int lda,
    const ushort* __restrict__ Bt, const float* __restrict__ bias,
    const void* __restrict__ resid, void* __restrict__ Cp, int ldc,
    int Mr, int Kd, int row0, int col0)
{
    ushort* As = lds;
    ushort* Bs = lds + 8192;

    const int t = threadIdx.x;
    const int lane = t & 63;
    const int w = t >> 6;
    const int wr = w >> 1, wc = w & 1;
    const int lr = lane & 15, lk = lane >> 4;

    f32x4 acc[4][4] = {};

    const int srow = t >> 4;
    const int skq  = (t & 15) * 4;
    const int sg   = (t & 15) >> 1;
    const int srem = (t & 1) * 8;

    const float*  Af = (const float*)Ap;
    const ushort* Ah = (const ushort*)Ap;

    short4 sa_[8], sb_[8];
    float4 fa_[8], f2_[8];

    const int nk = Kd >> 6;

    auto issue = [&](int kk0) {
        #pragma unroll
        for (int p = 0; p < 8; ++p) {
            const int gr = min(row0 + p * 16 + srow, Mr - 1);
            if constexpr (A_BF16) {
                sa_[p] = *reinterpret_cast<const short4*>(Ah + (size_t)gr * lda + kk0 + skq);
            } else {
                fa_[p] = *reinterpret_cast<const float4*>(Af + (size_t)gr * lda + kk0 + skq);
                if constexpr (ADD_A2)
                    f2_[p] = *reinterpret_cast<const float4*>(A2 + (size_t)gr * lda + kk0 + skq);
            }
            sb_[p] = *reinterpret_cast<const short4*>(Bt + (size_t)(col0 + p * 16 + srow) * Kd + kk0 + skq);
        }
    };

    issue(0);

    for (int kt = 0; kt < nk; ++kt) {
        #pragma unroll
        for (int p = 0; p < 8; ++p) {
            const int r = p * 16 + srow;
            short4 a4;
            if constexpr (A_BF16) {
                a4 = sa_[p];
            } else {
                float4 av = fa_[p];
                if constexpr (ADD_A2) {
                    av.x += f2_[p].x; av.y += f2_[p].y; av.z += f2_[p].z; av.w += f2_[p].w;
                }
                a4.x = f2bf(av.x); a4.y = f2bf(av.y); a4.z = f2bf(av.z); a4.w = f2bf(av.w);
            }
            const int byteA = r * 128 + ((sg ^ (r & 7)) << 4) + srem;
            *reinterpret_cast<short4*>((char*)As + byteA) = a4;
            *reinterpret_cast<short4*>((char*)Bs + byteA) = sb_[p];
        }
        __syncthreads();

        if (kt + 1 < nk) issue((kt + 1) * 64);

        #pragma unroll
        for (int kk = 0; kk < 2; ++kk) {
            short8 af[4], bfr[4];
            #pragma unroll
            for (int i = 0; i < 4; ++i) {
                const int r = wr * 64 + i * 16 + lr;
                const int byte = r * 128 + (((kk * 4 + lk) ^ (r & 7)) << 4);
                af[i] = *reinterpret_cast<const short8*>((char*)As + byte);
            }
            #pragma unroll
            for (int j = 0; j < 4; ++j) {
                const int r = wc * 64 + j * 16 + lr;
                const int byte = r * 128 + (((kk * 4 + lk) ^ (r & 7)) << 4);
                bfr[j] = *reinterpret_cast<const short8*>((char*)Bs + byte);
            }
            #pragma unroll
            for (int i = 0; i < 4; ++i)
                #pragma unroll
                for (int j = 0; j < 4; ++j)
                    acc[i][j] = __builtin_amdgcn_mfma_f32_16x16x32_bf16(af[i], bfr[j], acc[i][j], 0, 0, 0);
        }
        __syncthreads();
    }

    if constexpr (OUT_BF16) {
        ushort* Cb = (ushort*)Cp;
        #pragma unroll
        for (int j = 0; j < 4; ++j) {
            const int lcol = wc * 64 + j * 16 + lr;
            const float bcol = bias[col0 + lcol];
            #pragma unroll
            for (int i = 0; i < 4; ++i) {
                const int lrbase = wr * 64 + i * 16 + lk * 4;
                #pragma unroll
                for (int reg = 0; reg < 4; ++reg) {
                    float v = acc[i][j][reg] + bcol;
                    if (RESID) {   // R16: resid support in bf16 epilogue (row-clamped)
                        const int rr = min(row0 + lrbase + reg, Mr - 1);
                        if (RESID_BF16)
                            v += bf2f(((const ushort*)resid)[(size_t)rr * ldc + col0 + lcol]);
                        else
                            v += ((const float*)resid)[(size_t)rr * ldc + col0 + lcol];
                    }
                    if (RELU) v = fmaxf(v, 0.f);
                    lds[(lrbase + reg) * EPS + lcol] = (ushort)f2bf(v);
                }
            }
        }
        __syncthreads();
        const int erow = t >> 1, ehalf = t & 1;
        if (row0 + erow < Mr) {
            ushort* dst = Cb + (size_t)(row0 + erow) * ldc + col0 + ehalf * 64;
            const ushort* src = lds + erow * EPS + ehalf * 64;
            #pragma unroll
            for (int q = 0; q < 8; ++q)
                *reinterpret_cast<short8*>(dst + q * 8) =
                    *reinterpret_cast<const short8*>(src + q * 8);
        }
    } else {
        float* Cf = (float*)Cp;
        #pragma unroll
        for (int j = 0; j < 4; ++j) {
            const int col = col0 + wc * 64 + j * 16 + lr;
            const float bcol = bias[col];
            #pragma unroll
            for (int i = 0; i < 4; ++i) {
                const int rbase = row0 + wr * 64 + i * 16 + lk * 4;
                #pragma unroll
                for (int reg = 0; reg < 4; ++reg) {
                    const int r = rbase + reg;
                    if (r < Mr) {
                        float v = acc[i][j][reg] + bcol;
                        if (RESID) {
                            if (RESID_BF16)
                                v += bf2f(((const ushort*)resid)[(size_t)r * ldc + col]);
                            else
                                v += ((const float*)resid)[(size_t)r * ldc + col];
                        }
                        if (RELU) v = fmaxf(v, 0.f);
                        Cf[(size_t)r * ldc + col] = v;
                    }
                }
            }
        }
    }
}

template<bool A_BF16, bool ADD_A2, bool RELU, bool RESID, bool RESID_BF16, bool OUT_BF16>
__global__ __launch_bounds__(256) void gemm_bf16(
    const void* __restrict__ Ap, const float* __restrict__ A2, int lda,
    const ushort* __restrict__ Bt, const float* __restrict__ bias,
    const void* __restrict__ resid, void* __restrict__ Cp, int ldc,
    int Mr, int Kd)
{
    __shared__ ushort lds[LDSN];
    gemm_core<A_BF16, ADD_A2, RELU, RESID, RESID_BF16, OUT_BF16>(
        lds, Ap, A2, lda, Bt, bias, resid, Cp, ldc, Mr, Kd,
        blockIdx.y * 128, blockIdx.x * 128);
}

// ---------------- MHA: bf16 MFMA flash attention ----------------
__global__ __launch_bounds__(256) void attn_mfma(
    const ushort* __restrict__ QKbf, const ushort* __restrict__ Vbf,
    ushort* __restrict__ attnO)
{
    __shared__ ushort K_lds[64][40];
    __shared__ ushort Vt[32][72];
    __shared__ ushort P_lds[4][16][72];

    const int t = threadIdx.x;
    const int w = t >> 6, lane = t & 63;
    const int q0 = blockIdx.x * 64;
    const int m = blockIdx.y & 7, b = blockIdx.y >> 3;

    const int lr = lane & 15;
    const int lk = lane >> 4;

    const int qrow = min(q0 + w * 16 + lr, LQ - 1);
    const short8 qf = *reinterpret_cast<const short8*>(
        QKbf + ((size_t)qrow * BB + b) * 512 + m * 32 + lk * 8);

    f32x4 oacc[2] = {f32x4{0.f,0.f,0.f,0.f}, f32x4{0.f,0.f,0.f,0.f}};
    float mrun[4] = {-1e30f, -1e30f, -1e30f, -1e30f};
    float lrun[4] = {0.f, 0.f, 0.f, 0.f};

    const float scale = 0.17677669529663687f; // 1/sqrt(32)
    const int sr = t >> 2;
    const int sd = (t & 3) * 8;

    for (int k0 = 0; k0 < LQ; k0 += 64) {
        {
            const int kr = min(k0 + sr, LQ - 1);
            *reinterpret_cast<short8*>(&K_lds[sr][sd]) =
                *reinterpret_cast<const short8*>(QKbf + ((size_t)kr * BB + b) * 512 + 256 + m * 32 + sd);
            const short8 v8 = *reinterpret_cast<const short8*>(
                Vbf + ((size_t)kr * BB + b) * 256 + m * 32 + sd);
            #pragma unroll
            for (int j = 0; j < 8; ++j) Vt[sd + j][sr] = (ushort)v8[j];
        }
        __syncthreads();

        f32x4 sa[4];
        #pragma unroll
        for (int n = 0; n < 4; ++n) {
            const short8 kf = *reinterpret_cast<const short8*>(&K_lds[n * 16 + lr][lk * 8]);
            sa[n] = __builtin_amdgcn_mfma_f32_16x16x32_bf16(qf, kf, f32x4{0.f,0.f,0.f,0.f}, 0, 0, 0);
        }
        #pragma unroll
        for (int n = 0; n < 4; ++n)
            #pragma unroll
            for (int r = 0; r < 4; ++r)
                sa[n][r] *= scale;
        if (k0 + 64 > LQ) {
            #pragma unroll
            for (int n = 0; n < 4; ++n)
                if (k0 + n * 16 + lr >= LQ) {
                    #pragma unroll
                    for (int r = 0; r < 4; ++r) sa[n][r] = -1e30f;
                }
        }

        #pragma unroll
        for (int r = 0; r < 4; ++r) {
            float mx = fmaxf(fmaxf(sa[0][r], sa[1][r]), fmaxf(sa[2][r], sa[3][r]));
            #pragma unroll
            for (int o = 8; o; o >>= 1) mx = fmaxf(mx, __shfl_xor(mx, o));
            const float mnew = fmaxf(mrun[r], mx);
            const float corr = __expf(mrun[r] - mnew);
            mrun[r] = mnew;
            float psum = 0.f;
            #pragma unroll
            for (int n = 0; n < 4; ++n) {
                const float p = __expf(sa[n][r] - mnew);
                psum += p;
                P_lds[w][lk * 4 + r][n * 16 + lr] = (ushort)f2bf(p);
            }
            #pragma unroll
            for (int o = 8; o; o >>= 1) psum += __shfl_xor(psum, o);
            lrun[r] = lrun[r] * corr + psum;
            oacc[0][r] *= corr;
            oacc[1][r] *= corr;
        }

        #pragma unroll
        for (int kk = 0; kk < 2; ++kk) {
            const short8 pf = *reinterpret_cast<const short8*>(&P_lds[w][lr][kk * 32 + lk * 8]);
            #pragma unroll
            for (int dt = 0; dt < 2; ++dt) {
                const short8 vf = *reinterpret_cast<const short8*>(&Vt[dt * 16 + lr][kk * 32 + lk * 8]);
                oacc[dt] = __builtin_amdgcn_mfma_f32_16x16x32_bf16(pf, vf, oacc[dt], 0, 0, 0);
            }
        }
        __syncthreads();
    }

    #pragma unroll
    for (int r = 0; r < 4; ++r) {
        const int row = q0 + w * 16 + lk * 4 + r;
        if (row < LQ) {
            const float inv = 1.f / lrun[r];
            ushort* op = attnO + ((size_t)row * BB + b) * 256 + m * 32;
            op[lr]      = (ushort)f2bf(oacc[0][r] * inv);
            op[16 + lr] = (ushort)f2bf(oacc[1][r] * inv);
        }
    }
}

// ---------------- layernorm: one wave per row of 256 ----------------
template<bool IN_BF16, bool OUT_BF16>
__global__ __launch_bounds__(256) void ln_kernel(
    const void* __restrict__ Xp, const float* __restrict__ g,
    const float* __restrict__ bta, void* __restrict__ Y, int nrows)
{
    const int r = blockIdx.x * 4 + (threadIdx.x >> 6);
    if (r >= nrows) return;
    const int lane = threadIdx.x & 63;
    float4 v;
    if (IN_BF16) {
        const short4 u = *reinterpret_cast<const short4*>(
            (const ushort*)Xp + (size_t)r * 256 + lane * 4);
        v.x = bf2f((ushort)u.x); v.y = bf2f((ushort)u.y);
        v.z = bf2f((ushort)u.z); v.w = bf2f((ushort)u.w);
    } else {
        v = *reinterpret_cast<const float4*>((const float*)Xp + (size_t)r * 256 + lane * 4);
    }
    float s  = v.x + v.y + v.z + v.w;
    float sq = v.x * v.x + v.y * v.y + v.z * v.z + v.w * v.w;
    #pragma unroll
    for (int o = 32; o; o >>= 1) { s += __shfl_xor(s, o); sq += __shfl_xor(sq, o); }
    const float mean = s * (1.f / 256.f);
    const float var  = sq * (1.f / 256.f) - mean * mean;
    const float rs   = rsqrtf(var + 1e-5f);
    const float4 gv = *reinterpret_cast<const float4*>(g + lane * 4);
    const float4 bv = *reinterpret_cast<const float4*>(bta + lane * 4);
    float4 o4;
    o4.x = (v.x - mean) * rs * gv.x + bv.x;
    o4.y = (v.y - mean) * rs * gv.y + bv.y;
    o4.z = (v.z - mean) * rs * gv.z + bv.z;
    o4.w = (v.w - mean) * rs * gv.w + bv.w;
    if (OUT_BF16) {
        short4 u;
        u.x = f2bf(o4.x); u.y = f2bf(o4.y); u.z = f2bf(o4.z); u.w = f2bf(o4.w);
        *reinterpret_cast<short4*>((ushort*)Y + (size_t)r * 256 + lane * 4) = u;
    } else {
        *reinterpret_cast<float4*>((float*)Y + (size_t)r * 256 + lane * 4) = o4;
    }
}

// ---------------- fused sampling: prep (softmax+bilinear) + gather ----------------
// obf (NROWS,384) bf16: cols 0..255 offsets, 256..383 aw logits.
__global__ __launch_bounds__(256) void samp_gather(
    const ushort* __restrict__ Vval, const ushort* __restrict__ obf,
    const float* __restrict__ ref, ushort* __restrict__ samp)
{
    __shared__ int   sI[4][16][4];
    __shared__ float sW[4][16][4];

    const int w    = threadIdx.x >> 6;
    const int lane = threadIdx.x & 63;
    const int wid  = blockIdx.x * 4 + w;           // < 115,200
    const int q  = wid % LQ;
    const int bm = wid / LQ;
    const int m  = bm & 7, b = bm >> 3;
    const int row = q * BB + b;

    if (lane < 16) {
        const float logit = bf2f(obf[(size_t)row * 384 + 256 + m * 16 + lane]);
        float mx = logit;
        #pragma unroll
        for (int o = 1; o < 16; o <<= 1) mx = fmaxf(mx, __shfl_xor(mx, o));
        const float e = __expf(logit - mx);
        float se = e;
        #pragma unroll
        for (int o = 1; o < 16; o <<= 1) se += __shfl_xor(se, o);
        const float aw = e / se;

        const int   l  = lane >> 2;
        const int   Hl = d_HW[l];
        const float Hf = (float)Hl;
        const int   gbase = d_baseR[l] + b * Hl * Hl;
        const float rx = ref[row * 2 + 0], ry = ref[row * 2 + 1];
        const float ox = bf2f(obf[(size_t)row * 384 + m * 32 + lane * 2 + 0]);
        const float oy = bf2f(obf[(size_t)row * 384 + m * 32 + lane * 2 + 1]);
        const float px = rx * Hf - 0.5f + ox;
        const float py = ry * Hf - 0.5f + oy;
        const float x0 = floorf(px), y0 = floorf(py);

        #pragma unroll
        for (int c = 0; c < 4; ++c) {
            const float xi = x0 + (float)(c & 1);
            const float yi = y0 + (float)(c >> 1);
            const float wv = (1.f - fabsf(px - xi)) * (1.f - fabsf(py - yi));
            const bool valid = (xi >= 0.f) && (xi < Hf) && (yi >= 0.f) && (yi < Hf);
            const int ix = min(max((int)xi, 0), Hl - 1);
            const int iy = min(max((int)yi, 0), Hl - 1);
            sI[w][lane][c] = gbase + iy * Hl + ix;
            sW[w][lane][c] = valid ? aw * wv : 0.f;
        }
    }
    // same-wave LDS write->read: program order + compiler waitcnt; no barrier needed.

    const int sid = lane >> 3, dg = lane & 7;
    const uint2* V4 = (const uint2*)Vval;
    const int coff  = m * 8 + dg;

    float a0 = 0.f, a1 = 0.f, a2 = 0.f, a3 = 0.f;
    #pragma unroll
    for (int g = 0; g < 2; ++g) {
        const int s = g * 8 + sid;
        const int4   I = *reinterpret_cast<const int4*>(&sI[w][s][0]);
        const float4 W = *reinterpret_cast<const float4*>(&sW[w][s][0]);
        uint2 v;
        v = V4[(size_t)I.x * 64 + coff];
        a0 += W.x * bf2f((ushort)v.x); a1 += W.x * bf2f((ushort)(v.x >> 16));
        a2 += W.x * bf2f((ushort)v.y); a3 += W.x * bf2f((ushort)(v.y >> 16));
        v = V4[(size_t)I.y * 64 + coff];
        a0 += W.y * bf2f((ushort)v.x); a1 += W.y * bf2f((ushort)(v.x >> 16));
        a2 += W.y * bf2f((ushort)v.y); a3 += W.y * bf2f((ushort)(v.y >> 16));
        v = V4[(size_t)I.z * 64 + coff];
        a0 += W.z * bf2f((ushort)v.x); a1 += W.z * bf2f((ushort)(v.x >> 16));
        a2 += W.z * bf2f((ushort)v.y); a3 += W.z * bf2f((ushort)(v.y >> 16));
        v = V4[(size_t)I.w * 64 + coff];
        a0 += W.w * bf2f((ushort)v.x); a1 += W.w * bf2f((ushort)(v.x >> 16));
        a2 += W.w * bf2f((ushort)v.y); a3 += W.w * bf2f((ushort)(v.y >> 16));
    }
    #pragma unroll
    for (int o = 8; o <= 32; o <<= 1) {
        a0 += __shfl_xor(a0, o); a1 += __shfl_xor(a1, o);
        a2 += __shfl_xor(a2, o); a3 += __shfl_xor(a3, o);
    }
    if (sid == 0) {
        short4 u;
        u.x = f2bf(a0); u.y = f2bf(a1); u.z = f2bf(a2); u.w = f2bf(a3);
        *reinterpret_cast<short4*>(samp + (size_t)row * 256 + m * 32 + dg * 4) = u;
    }
}

// ---------------- launcher ----------------
extern "C" void kernel_launch(void* const* d_in, const int* in_sizes, int n_in,
                              void* d_out, int out_size, void* d_ws, size_t ws_size,
                              hipStream_t stream)
{
    const float* qo   = (const float*)d_in[0];
    const float* qpz  = (const float*)d_in[1];
    const float* refp = (const float*)d_in[2];
    const float* feat[4] = {(const float*)d_in[3], (const float*)d_in[5],
                            (const float*)d_in[7], (const float*)d_in[9]};
    const float* pos[4]  = {(const float*)d_in[4], (const float*)d_in[6],
                            (const float*)d_in[8], (const float*)d_in[10]};
    const float* sa_in_w  = (const float*)d_in[11];
    const float* sa_in_b  = (const float*)d_in[12];
    const float* sa_out_w = (const float*)d_in[13];
    const float* sa_out_b = (const float*)d_in[14];
    const float* n1_g = (const float*)d_in[15];
    const float* n1_b = (const float*)d_in[16];
    const float* n2_g = (const float*)d_in[17];
    const float* n2_b = (const float*)d_in[18];
    const float* n3_g = (const float*)d_in[19];
    const float* n3_b = (const float*)d_in[20];
    const float* val_w  = (const float*)d_in[21];
    const float* val_b  = (const float*)d_in[22];
    const float* off_w  = (const float*)d_in[23];
    const float* off_b  = (const float*)d_in[24];
    const float* aw_w   = (const float*)d_in[25];
    const float* aw_b   = (const float*)d_in[26];
    const float* dout_w = (const float*)d_in[27];
    const float* dout_b = (const float*)d_in[28];
    const float* ffn_w1 = (const float*)d_in[29];
    const float* ffn_b1 = (const float*)d_in[30];
    const float* ffn_w2 = (const float*)d_in[31];
    const float* ffn_b2 = (const float*)d_in[32];

    char* ws = (char*)d_ws;
    // bf16 buffers
    ushort* QKbf   = (ushort*)(ws + 0);             // 14,745,600
    ushort* Vbf    = (ushort*)(ws + 14745600);      // 7,372,800
    ushort* attnO  = (ushort*)(ws + 22118400);      // 7,372,800
    ushort* Vval   = (ushort*)(ws + 29491200);      // 108,904,448
    ushort* WsaInT = (ushort*)(ws + 138395648);     // 393,216
    ushort* WsaOutT= (ushort*)(ws + 138788864);     // 131,072
    ushort* WvalT  = (ushort*)(ws + 138919936);     // 131,072
    ushort* WdoutT = (ushort*)(ws + 139051008);     // 131,072
    ushort* Wffn1T = (ushort*)(ws + 139182080);     // 524,288
    ushort* Wffn2T = (ushort*)(ws + 139706368);     // 524,288
    ushort* WoffAwT= (ushort*)(ws + 140230656);     // 196,608
    float*  obias  = (float*)(ws + 140427264);      // 2,048
    // residual-stream buffers (R16: bf16)
    ushort* x1   = (ushort*)(ws + 140429312);       // 7,372,800 (bf16)
    ushort* dres = x1;
    ushort* xln1 = (ushort*)(ws + 147802112);       // 7,372,800 (bf16)
    ushort* obf  = (ushort*)(ws + 155174912);       // 11,059,200 (bf16, (NROWS,384))
    ushort* samp = (ushort*)(ws + 166234112);       // 7,372,800 (bf16)
    ushort* xln2 = (ushort*)(ws + 173606912);       // 7,372,800 (bf16)
    ushort* h    = (ushort*)(ws + 180979712);       // 29,491,200 (bf16)
    ushort* x3   = (ushort*)(ws + 210470912);       // 7,372,800 (bf16) -> ends 217,843,712

    const dim3 blk(256);
    const int GM = (NROWS + 127) / 128;             // 113

    // 0. all weight transposes + bias concat in ONE launch
    WPack wp;
    wp.W[0] = sa_in_w;  wp.Wt[0] = WsaInT;  wp.K[0] = 256;  wp.N[0] = 768;
    wp.W[1] = sa_out_w; wp.Wt[1] = WsaOutT; wp.K[1] = 256;  wp.N[1] = 256;
    wp.W[2] = val_w;    wp.Wt[2] = WvalT;   wp.K[2] = 256;  wp.N[2] = 256;
    wp.W[3] = dout_w;   wp.Wt[3] = WdoutT;  wp.K[3] = 256;  wp.N[3] = 256;
    wp.W[4] = ffn_w1;   wp.Wt[4] = Wffn1T;  wp.K[4] = 256;  wp.N[4] = 1024;
    wp.W[5] = ffn_w2;   wp.Wt[5] = Wffn2T;  wp.K[5] = 1024; wp.N[5] = 256;
    wp.W[6] = off_w;    wp.Wt[6] = WoffAwT; wp.K[6] = 256;  wp.N[6] = 256;
    wp.W[7] = aw_w;     wp.Wt[7] = WoffAwT + 256 * 256; wp.K[7] = 256; wp.N[7] = 128;
    const int cums[9] = {0, 192, 256, 320, 384, 640, 896, 960, 992};
    for (int i = 0; i < 9; ++i) wp.cum[i] = cums[i];
    wp.offb = off_b; wp.awb = aw_b; wp.obias = obias;
    conv_all<<<dim3(993), blk, 0, stream>>>(wp);

    // 1. Q,K projections (A = qo+qpz, fp32 fused add) -> QKbf
    gemm_bf16<false, true, false, false, false, true><<<dim3(4, GM), blk, 0, stream>>>(
        qo, qpz, 256, WsaInT, sa_in_b, nullptr, QKbf, 512, NROWS, 256);
    // 2. V projection (A = qo fp32) -> Vbf
    gemm_bf16<false, false, false, false, false, true><<<dim3(2, GM), blk, 0, stream>>>(
        qo, nullptr, 256, WsaInT + 512 * 256, sa_in_b + 512, nullptr, Vbf, 256, NROWS, 256);
    // 3. self-attention
    attn_mfma<<<dim3(15, 128), blk, 0, stream>>>(QKbf, Vbf, attnO);
    // 4. out projection + residual(qo f32) -> x1 bf16
    gemm_bf16<true, false, false, true, false, true><<<dim3(2, GM), blk, 0, stream>>>(
        attnO, nullptr, 256, WsaOutT, sa_out_b, qo, x1, 256, NROWS, 256);
    // 5. LN1 (in bf16) -> xln1 bf16
    ln_kernel<true, true><<<dim3(3600), blk, 0, stream>>>(x1, n1_g, n1_b, xln1, NROWS);
    // 6. fused offsets + aw logits -> obf bf16 (N=384), A = xln1 bf16
    gemm_bf16<true, false, false, false, false, true><<<dim3(3, GM), blk, 0, stream>>>(
        xln1, nullptr, 256, WoffAwT, obias, nullptr, obf, 384, NROWS, 256);
    // 7. value projections per level (proven 2-phase engine, fp32 fused add)
    gemm_bf16<false, true, false, false, false, true><<<dim3(2, 1250), blk, 0, stream>>>(
        feat[0], pos[0], 256, WvalT, val_b, nullptr, Vval, 256, 160000, 256);
    gemm_bf16<false, true, false, false, false, true><<<dim3(2, 313), blk, 0, stream>>>(
        feat[1], pos[1], 256, WvalT, val_b, nullptr, Vval + (size_t)160000 * 256, 256, 40000, 256);
    gemm_bf16<false, true, false, false, false, true><<<dim3(2, 79), blk, 0, stream>>>(
        feat[2], pos[2], 256, WvalT, val_b, nullptr, Vval + (size_t)200000 * 256, 256, 10000, 256);
    gemm_bf16<false, true, false, false, false, true><<<dim3(2, 22), blk, 0, stream>>>(
        feat[3], pos[3], 256, WvalT, val_b, nullptr, Vval + (size_t)210000 * 256, 256, 2704, 256);
    // 8. fused prep+gather -> samp bf16
    samp_gather<<<dim3(28800), blk, 0, stream>>>(Vval, obf, refp, samp);
    // 9. deform output projection (A=samp bf16) + residual(xln1 bf16) -> dres bf16
    gemm_bf16<true, false, false, true, true, true><<<dim3(2, GM), blk, 0, stream>>>(
        samp, nullptr, 256, WdoutT, dout_b, xln1, dres, 256, NROWS, 256);
    // 10. LN2 (in bf16) -> xln2 bf16
    ln_kernel<true, true><<<dim3(3600), blk, 0, stream>>>(dres, n2_g, n2_b, xln2, NROWS);
    // 11. FFN1 (relu), A = xln2 bf16 -> h bf16
    gemm_bf16<true, false, true, false, false, true><<<dim3(8, GM), blk, 0, stream>>>(
        xln2, nullptr, 256, Wffn1T, ffn_b1, nullptr, h, 1024, NROWS, 256);
    // 12. FFN2 + residual(xln2 bf16) -> x3 bf16
    gemm_bf16<true, false, false, true, true, true><<<dim3(2, GM), blk, 0, stream>>>(
        h, nullptr, 1024, Wffn2T, ffn_b2, xln2, x3, 256, NROWS, 1024);
    // 13. LN3 (in bf16) -> output f32
    ln_kernel<true, false><<<dim3(3600), blk, 0, stream>>>(x3, n3_g, n3_b, (float*)d_out, NROWS);
}